// Round 4
// baseline (49.769 us; speedup 1.0000x reference)
//
#include <hip/hip_runtime.h>

// Masking: x[B=8, L=2048, C=64, D=32] f32; zero x[:, s:s+len, ch, :] for 16 blocks.
// Memory-bound masked copy. 128 MiB in + 128 MiB out = exactly MALL capacity.
// R3 finding: nt-stores did NOT reduce FETCH (65.5 MB = input/2, byte-identical
// to plain stores) -> input and output each stay ~half MALL-resident.
// HBM stream is write-dominated (~2.8 TB/s of writes). This round inverts the
// hint: NT LOADS (reads have zero reuse within a replay -> don't allocate,
// don't evict output) + PLAIN STORES (let output stay dirty in MALL and
// absorb writebacks across graph replays).

#define BB 8
#define LL 2048
#define CC 64
#define DD 32
#define NBLK 16

typedef float v4f __attribute__((ext_vector_type(4)));

__global__ __launch_bounds__(256) void masking_kernel(
    const v4f* __restrict__ x,
    const int* __restrict__ starts,
    const int* __restrict__ lengths,
    const int* __restrict__ channels,
    v4f* __restrict__ out,
    int n4)
{
    // Block descriptors -> registers (wave-uniform scalar loads, hoisted).
    int st[NBLK], en[NBLK], ch[NBLK];
#pragma unroll
    for (int n = 0; n < NBLK; ++n) {
        st[n] = starts[n];
        en[n] = st[n] + lengths[n];
        ch[n] = channels[n];
    }

    const int stride = gridDim.x * blockDim.x;
    int i = blockIdx.x * blockDim.x + threadIdx.x;

    // 2-way unrolled grid-stride loop: two independent load/mask/store chains.
    for (; i + stride < n4; i += 2 * stride) {
        const int i0 = i;
        const int i1 = i + stride;

        v4f v0 = __builtin_nontemporal_load(&x[i0]);
        v4f v1 = __builtin_nontemporal_load(&x[i1]);

        const int lc0 = i0 >> 3;
        const int c0  = lc0 & (CC - 1);
        const int l0  = (lc0 >> 6) & (LL - 1);
        const int lc1 = i1 >> 3;
        const int c1  = lc1 & (CC - 1);
        const int l1  = (lc1 >> 6) & (LL - 1);

        bool z0 = false, z1 = false;
#pragma unroll
        for (int n = 0; n < NBLK; ++n) {
            z0 |= (c0 == ch[n]) & (l0 >= st[n]) & (l0 < en[n]);
            z1 |= (c1 == ch[n]) & (l1 >= st[n]) & (l1 < en[n]);
        }
        const float m0 = z0 ? 0.0f : 1.0f;
        const float m1 = z1 ? 0.0f : 1.0f;

        out[i0] = v0 * m0;
        out[i1] = v1 * m1;
    }
    // Tail (exact division here: 8 iters/thread, but keep it safe).
    if (i < n4) {
        const int lc = i >> 3;
        const int c  = lc & (CC - 1);
        const int l  = (lc >> 6) & (LL - 1);
        bool z = false;
#pragma unroll
        for (int n = 0; n < NBLK; ++n) {
            z |= (c == ch[n]) & (l >= st[n]) & (l < en[n]);
        }
        const float m = z ? 0.0f : 1.0f;
        v4f v = __builtin_nontemporal_load(&x[i]);
        out[i] = v * m;
    }
}

extern "C" void kernel_launch(void* const* d_in, const int* in_sizes, int n_in,
                              void* d_out, int out_size, void* d_ws, size_t ws_size,
                              hipStream_t stream)
{
    const v4f* x         = (const v4f*)d_in[0];
    const int* starts    = (const int*)d_in[1];
    const int* lengths   = (const int*)d_in[2];
    const int* channels  = (const int*)d_in[3];
    v4f* out             = (v4f*)d_out;

    const int n4 = (BB * LL * CC * DD) / 4;   // 8,388,608 float4s
    const int threads = 256;
    const int blocks = 4096;                  // 8 grid-stride iters/thread

    masking_kernel<<<blocks, threads, 0, stream>>>(x, starts, lengths, channels, out, n4);
}

// Round 5
// 45.724 us; speedup vs baseline: 1.0885x; 1.0885x over previous
//
#include <hip/hip_runtime.h>

// Masking: x[B=8, L=2048, C=64, D=32] f32; zero x[:, s:s+len, ch, :] for 16 blocks.
// Memory-bound masked copy. Best so far (R3): nt-stores, 4096x256, 2-way unroll = 46.5us.
// R4: nt-loads hurt -> reverted.
// This round: stride 4096*256 float4s is an exact multiple of L*C*8, so each
// thread's 8 grid-stride items share the same (l,c) -> compute the mask ONCE
// per thread, fully unroll the 8 b-iterations as 8 independent load/store
// pairs (8x16B outstanding per lane).

#define BB 8
#define LL 2048
#define CC 64
#define DD 32
#define NBLK 16

typedef float v4f __attribute__((ext_vector_type(4)));

__global__ __launch_bounds__(256) void masking_kernel(
    const v4f* __restrict__ x,
    const int* __restrict__ starts,
    const int* __restrict__ lengths,
    const int* __restrict__ channels,
    v4f* __restrict__ out)
{
    // Block descriptors -> registers (wave-uniform scalar loads).
    int st[NBLK], en[NBLK], ch[NBLK];
#pragma unroll
    for (int n = 0; n < NBLK; ++n) {
        st[n] = starts[n];
        en[n] = st[n] + lengths[n];
        ch[n] = channels[n];
    }

    // tid in [0, L*C*8): indexes (l, c, d4). The 8 batches b are at
    // tid + b*STRIDE, STRIDE = L*C*8 float4s. (l,c) identical across b.
    const int tid = blockIdx.x * blockDim.x + threadIdx.x;
    const int STRIDE = LL * CC * (DD / 4);     // 1,048,576 float4s

    const int lc = tid >> 3;
    const int c  = lc & (CC - 1);
    const int l  = lc >> 6;                    // < LL by construction

    bool z = false;
#pragma unroll
    for (int n = 0; n < NBLK; ++n) {
        z |= (c == ch[n]) & (l >= st[n]) & (l < en[n]);
    }
    const float m = z ? 0.0f : 1.0f;

    // 8 independent load/store pairs; loads issued back-to-back for MLP.
    v4f v[BB];
#pragma unroll
    for (int b = 0; b < BB; ++b) {
        v[b] = x[tid + b * STRIDE];
    }
#pragma unroll
    for (int b = 0; b < BB; ++b) {
        __builtin_nontemporal_store(v[b] * m, &out[tid + b * STRIDE]);
    }
}

extern "C" void kernel_launch(void* const* d_in, const int* in_sizes, int n_in,
                              void* d_out, int out_size, void* d_ws, size_t ws_size,
                              hipStream_t stream)
{
    const v4f* x         = (const v4f*)d_in[0];
    const int* starts    = (const int*)d_in[1];
    const int* lengths   = (const int*)d_in[2];
    const int* channels  = (const int*)d_in[3];
    v4f* out             = (v4f*)d_out;

    const int threads = 256;
    const int blocks  = (LL * CC * (DD / 4)) / threads;  // 4096; exact cover, no tail

    masking_kernel<<<blocks, threads, 0, stream>>>(x, starts, lengths, channels, out);
}

// Round 6
// 44.850 us; speedup vs baseline: 1.1097x; 1.0195x over previous
//
#include <hip/hip_runtime.h>

// Masking: x[B=8, L=2048, C=64, D=32] f32; zero x[:, s:s+len, ch, :] for 16 blocks.
// Memory-bound masked copy; logical traffic fixed at 268 MB/replay.
// R5 = 45.7us = 93% of the 6.29 TB/s d2d ceiling. VALUBusy 3.9%, FETCH pinned
// at input/2 (MALL equilibrium). This round probes dispatch/ramp shape only:
// 1024 blocks x 1024 threads (2 resident blocks/CU, 16 waves/CU) instead of
// 4096 x 256. Same total work, same mask-once-per-thread property
// (stride = L*C*8 float4s keeps (l,c) invariant across the 8 b-iterations).

#define BB 8
#define LL 2048
#define CC 64
#define DD 32
#define NBLK 16

typedef float v4f __attribute__((ext_vector_type(4)));

__global__ __launch_bounds__(1024) void masking_kernel(
    const v4f* __restrict__ x,
    const int* __restrict__ starts,
    const int* __restrict__ lengths,
    const int* __restrict__ channels,
    v4f* __restrict__ out)
{
    // Block descriptors -> registers (wave-uniform scalar loads).
    int st[NBLK], en[NBLK], ch[NBLK];
#pragma unroll
    for (int n = 0; n < NBLK; ++n) {
        st[n] = starts[n];
        en[n] = st[n] + lengths[n];
        ch[n] = channels[n];
    }

    // tid in [0, L*C*8): indexes (l, c, d4). The 8 batches b are at
    // tid + b*STRIDE, STRIDE = L*C*8 float4s. (l,c) identical across b.
    const int tid = blockIdx.x * blockDim.x + threadIdx.x;
    const int STRIDE = LL * CC * (DD / 4);     // 1,048,576 float4s

    const int lc = tid >> 3;
    const int c  = lc & (CC - 1);
    const int l  = lc >> 6;                    // < LL by construction

    bool z = false;
#pragma unroll
    for (int n = 0; n < NBLK; ++n) {
        z |= (c == ch[n]) & (l >= st[n]) & (l < en[n]);
    }
    const float m = z ? 0.0f : 1.0f;

    // 8 independent load/store pairs; loads issued back-to-back for MLP.
    v4f v[BB];
#pragma unroll
    for (int b = 0; b < BB; ++b) {
        v[b] = x[tid + b * STRIDE];
    }
#pragma unroll
    for (int b = 0; b < BB; ++b) {
        __builtin_nontemporal_store(v[b] * m, &out[tid + b * STRIDE]);
    }
}

extern "C" void kernel_launch(void* const* d_in, const int* in_sizes, int n_in,
                              void* d_out, int out_size, void* d_ws, size_t ws_size,
                              hipStream_t stream)
{
    const v4f* x         = (const v4f*)d_in[0];
    const int* starts    = (const int*)d_in[1];
    const int* lengths   = (const int*)d_in[2];
    const int* channels  = (const int*)d_in[3];
    v4f* out             = (v4f*)d_out;

    const int threads = 1024;
    const int blocks  = (LL * CC * (DD / 4)) / threads;  // 1024; exact cover, no tail

    masking_kernel<<<blocks, threads, 0, stream>>>(x, starts, lengths, channels, out);
}